// Round 10
// baseline (197.546 us; speedup 1.0000x reference)
//
#include <hip/hip_runtime.h>

#define N_NODES 50000
#define N_EDGES 1600000
#define HEADS 4
#define DPH 16
#define F_IN 128
#define HD 64   // HEADS * DPH
#define NCHAIN 16

#define QKV_BLOCKS 1563            // ceil(50000/32)
#define LINK_BLOCKS 1563
#define TOTAL_BLOCKS 3126          // parity-interleaved roles
#define LINK_STRIDE (LINK_BLOCKS * 512)

__device__ inline unsigned pack_bf16(float k, float v) {
    unsigned uk = __float_as_uint(k), uv = __float_as_uint(v);
    uk = (uk + 0x7FFFu + ((uk >> 16) & 1u)) >> 16;   // RNE to bf16
    uv = (uv + 0x7FFFu + ((uv >> 16) & 1u)) >> 16;
    return (uv << 16) | uk;
}

// ---------------------------------------------------------------------------
// Fat kernel, parity-interleaved roles.
// qkv role (even blocks): 32 nodes/block, 512 threads. Waves 0-5 compute
// (m = wave>>1 selects Q/K/V, wave&1 selects node half; each lane owns a
// 4-node x 4-col f32 tile). W is read once per 32 nodes -> 154 MB L2
// traffic (halved vs round 9) to decongest the L2 atomic path.
// link role (odd blocks): 16 interleaved chains/node, ONE atomicExch per
// edge — the ~19G line-req/s memory-side atomic law floor.
// ---------------------------------------------------------------------------
__global__ void __launch_bounds__(512)
qkv_and_links(const float* __restrict__ x,
              const float* __restrict__ Wq,
              const float* __restrict__ Wk,
              const float* __restrict__ Wv,
              const int* __restrict__ src,
              const int* __restrict__ dst,
              float* __restrict__ Q,
              unsigned* __restrict__ KV,
              int* __restrict__ head,
              int2* __restrict__ elink) {
    const int bx = blockIdx.x;
    const int tid = threadIdx.x;

    if (bx & 1) {
        // ---- link-build role ----
        const int bid = bx >> 1;
        for (int i = bid * 512 + tid; i < N_EDGES; i += LINK_STRIDE) {
            const int d = dst[i];
            const int nx = atomicExch(&head[d * NCHAIN + (i & (NCHAIN - 1))], i);
            elink[i] = make_int2(src[i], nx);
        }
        return;
    }

    // ---- qkv role ----
    const int qb = bx >> 1;
    const int node0 = qb * 32;

    __shared__ float xs[32][F_IN + 4];   // +4 pad
    __shared__ float kcol[32][68];
    __shared__ float vcol[32][68];

    // stage 32 node rows (guard the ragged last block)
    for (int i = tid; i < 1024; i += 512) {          // 1024 float4 = 32 x 32
        const int r = i >> 5, c4 = (i & 31) * 4;
        const int n = node0 + r;
        *(float4*)&xs[r][c4] = (n < N_NODES)
            ? *(const float4*)&x[(size_t)n * F_IN + c4]
            : make_float4(0.f, 0.f, 0.f, 0.f);
    }
    __syncthreads();

    const int w = tid >> 6;          // wave 0..7
    const int lane = tid & 63;
    const int m = w >> 1;            // 0=Q, 1=K, 2=V (waves 6,7 idle here)
    const int nh = w & 1;            // node half
    const int cg = (lane & 15) * 4;              // col base
    const int ng = nh * 16 + (lane >> 4) * 4;    // node base

    if (m < 3) {
        const float* W = (m == 0) ? Wq : (m == 1) ? Wk : Wv;
        float acc[4][4];
        #pragma unroll
        for (int i = 0; i < 4; ++i)
            #pragma unroll
            for (int j = 0; j < 4; ++j) acc[i][j] = 0.f;

        for (int k = 0; k < F_IN; k += 4) {
            const float4 xv0 = *(const float4*)&xs[ng + 0][k];
            const float4 xv1 = *(const float4*)&xs[ng + 1][k];
            const float4 xv2 = *(const float4*)&xs[ng + 2][k];
            const float4 xv3 = *(const float4*)&xs[ng + 3][k];
            const float4 w0 = *(const float4*)&W[(k + 0) * HD + cg];
            const float4 w1 = *(const float4*)&W[(k + 1) * HD + cg];
            const float4 w2 = *(const float4*)&W[(k + 2) * HD + cg];
            const float4 w3 = *(const float4*)&W[(k + 3) * HD + cg];
            #pragma unroll
            for (int i = 0; i < 4; ++i) {
                const float4 xv = (i == 0) ? xv0 : (i == 1) ? xv1 : (i == 2) ? xv2 : xv3;
                acc[i][0] += xv.x * w0.x + xv.y * w1.x + xv.z * w2.x + xv.w * w3.x;
                acc[i][1] += xv.x * w0.y + xv.y * w1.y + xv.z * w2.y + xv.w * w3.y;
                acc[i][2] += xv.x * w0.z + xv.y * w1.z + xv.z * w2.z + xv.w * w3.z;
                acc[i][3] += xv.x * w0.w + xv.y * w1.w + xv.z * w2.w + xv.w * w3.w;
            }
        }

        if (m == 0) {
            #pragma unroll
            for (int i = 0; i < 4; ++i) {
                const int n = node0 + ng + i;
                if (n < N_NODES)
                    *(float4*)&Q[(size_t)n * HD + cg] =
                        make_float4(acc[i][0], acc[i][1], acc[i][2], acc[i][3]);
            }
        } else if (m == 1) {
            #pragma unroll
            for (int i = 0; i < 4; ++i)
                *(float4*)&kcol[ng + i][cg] =
                    make_float4(acc[i][0], acc[i][1], acc[i][2], acc[i][3]);
        } else {
            #pragma unroll
            for (int i = 0; i < 4; ++i)
                *(float4*)&vcol[ng + i][cg] =
                    make_float4(acc[i][0], acc[i][1], acc[i][2], acc[i][3]);
        }
    }
    __syncthreads();

    // pack K,V -> interleaved bf16 (all 512 threads, 4 entries each)
    for (int i = tid; i < 32 * 64; i += 512) {
        const int nn = i >> 6, cc = i & 63;
        const int n = node0 + nn;
        if (n < N_NODES)
            KV[(size_t)n * HD + cc] = pack_bf16(kcol[nn][cc], vcol[nn][cc]);
    }
}

// ---------------------------------------------------------------------------
// Gather: one wave per node. lane = t*4 + h; the 4 h-lanes of chain-slot t
// walk chain t together (elink load broadcasts, each h-lane loads its own
// 64B KV slice). Hot loop fully lane-local; epilogue reduce-scatter.
// ---------------------------------------------------------------------------
__global__ void gather_chains(const int* __restrict__ head,
                              const int2* __restrict__ elink,
                              const float* __restrict__ Q,
                              const unsigned* __restrict__ KV,
                              float* __restrict__ out) {
    const int n = blockIdx.x * 4 + (threadIdx.x >> 6);
    if (n >= N_NODES) return;
    const int lane = threadIdx.x & 63;
    const int t = lane >> 2;   // chain slot 0..15
    const int h = lane & 3;    // head

    float qv[16];
    {
        const float4* qp = (const float4*)(Q + (size_t)n * HD + h * DPH);
        #pragma unroll
        for (int j = 0; j < 4; ++j) {
            const float4 f = qp[j];
            qv[4 * j + 0] = f.x; qv[4 * j + 1] = f.y;
            qv[4 * j + 2] = f.z; qv[4 * j + 3] = f.w;
        }
    }

    float acc[16];
    #pragma unroll
    for (int j = 0; j < 16; ++j) acc[j] = 0.f;
    float zacc = 0.f;

    int e = head[n * NCHAIN + t];
    while (__ballot(e >= 0)) {
        if (e >= 0) {
            const int2 l = elink[e];
            const uint4* kp = (const uint4*)(KV + (size_t)l.x * HD + h * DPH);
            const uint4 w0 = kp[0], w1 = kp[1], w2 = kp[2], w3 = kp[3];
            const unsigned kw[16] = {w0.x, w0.y, w0.z, w0.w,
                                     w1.x, w1.y, w1.z, w1.w,
                                     w2.x, w2.y, w2.z, w2.w,
                                     w3.x, w3.y, w3.z, w3.w};
            float p = 0.f;
            #pragma unroll
            for (int j = 0; j < 16; ++j)
                p = fmaf(__uint_as_float(kw[j] << 16), qv[j], p);
            p = fminf(fmaxf(p * 0.25f, -5.f), 5.f);
            const float sc = __expf(p);
            #pragma unroll
            for (int j = 0; j < 16; ++j)
                acc[j] = fmaf(sc, __uint_as_float(kw[j] & 0xFFFF0000u), acc[j]);
            zacc += sc;
            e = l.y;
        }
    }

    // Reduce-scatter over t bits (masks 32,16,8,4 -> element bits 3,2,1,0).
    {
        const bool b = (lane & 32) != 0;
        float send[8], keep[8];
        #pragma unroll
        for (int j = 0; j < 8; ++j) {
            send[j] = b ? acc[j] : acc[j + 8];
            keep[j] = b ? acc[j + 8] : acc[j];
        }
        #pragma unroll
        for (int j = 0; j < 8; ++j) acc[j] = keep[j] + __shfl_xor(send[j], 32, 64);
    }
    {
        const bool b = (lane & 16) != 0;
        float send[4], keep[4];
        #pragma unroll
        for (int j = 0; j < 4; ++j) {
            send[j] = b ? acc[j] : acc[j + 4];
            keep[j] = b ? acc[j + 4] : acc[j];
        }
        #pragma unroll
        for (int j = 0; j < 4; ++j) acc[j] = keep[j] + __shfl_xor(send[j], 16, 64);
    }
    {
        const bool b = (lane & 8) != 0;
        float send[2], keep[2];
        #pragma unroll
        for (int j = 0; j < 2; ++j) {
            send[j] = b ? acc[j] : acc[j + 2];
            keep[j] = b ? acc[j + 2] : acc[j];
        }
        #pragma unroll
        for (int j = 0; j < 2; ++j) acc[j] = keep[j] + __shfl_xor(send[j], 8, 64);
    }
    {
        const bool b = (lane & 4) != 0;
        const float send = b ? acc[0] : acc[1];
        const float keep = b ? acc[1] : acc[0];
        acc[0] = keep + __shfl_xor(send, 4, 64);
    }

    // z: butterfly over the 16 t-lanes (h bits untouched)
    zacc += __shfl_xor(zacc, 4, 64);
    zacc += __shfl_xor(zacc, 8, 64);
    zacc += __shfl_xor(zacc, 16, 64);
    zacc += __shfl_xor(zacc, 32, 64);

    out[(size_t)n * HD + h * DPH + t] = acc[0] / (zacc + 1e-6f);
}

extern "C" void kernel_launch(void* const* d_in, const int* in_sizes, int n_in,
                              void* d_out, int out_size, void* d_ws, size_t ws_size,
                              hipStream_t stream) {
    const float* x   = (const float*)d_in[0];
    const int*   src = (const int*)d_in[1];
    const int*   dst = (const int*)d_in[2];
    const float* Wq  = (const float*)d_in[3];
    const float* Wk  = (const float*)d_in[4];
    const float* Wv  = (const float*)d_in[5];
    float* out = (float*)d_out;

    float*    Q     = (float*)d_ws;                          // 3.2M f32
    unsigned* KV    = (unsigned*)(Q + (size_t)N_NODES * HD); // 3.2M u32
    int2*     elink = (int2*)(KV + (size_t)N_NODES * HD);    // E int2
    int*      head  = (int*)(elink + (size_t)N_EDGES);       // N*16 int

    hipMemsetAsync(head, 0xFF, (size_t)N_NODES * NCHAIN * sizeof(int), stream);

    qkv_and_links<<<TOTAL_BLOCKS, 512, 0, stream>>>(x, Wq, Wk, Wv, src, dst,
                                                    Q, KV, head, elink);
    gather_chains<<<(N_NODES + 3) / 4, 256, 0, stream>>>(head, elink, Q, KV, out);
}